// Round 2
// baseline (1265.067 us; speedup 1.0000x reference)
//
#include <hip/hip_runtime.h>
#include <stdint.h>

#define BB 2
#define LL 2048
#define DD 1024
#define HH 16
#define DKK 64

typedef __attribute__((ext_vector_type(8))) short short8;
typedef __attribute__((ext_vector_type(4))) float f32x4;

__device__ __forceinline__ unsigned short f2bf(float x) {
    union { float f; unsigned int u; } v; v.f = x;
    unsigned int r = v.u + 0x7FFFu + ((v.u >> 16) & 1u);
    return (unsigned short)(r >> 16);
}

// ---------------- W fp32 -> bf16 ----------------
__global__ __launch_bounds__(256) void k_convw(
        const float* __restrict__ w0, const float* __restrict__ w1,
        const float* __restrict__ w2, const float* __restrict__ w3,
        unsigned short* __restrict__ dst) {
    int which = blockIdx.y;
    const float* s = which==0?w0: which==1?w1: which==2?w2: w3;
    unsigned short* d = dst + (size_t)which * (DD*DD);
    int i = (blockIdx.x * 256 + threadIdx.x) * 4;
    float4 f = *(const float4*)(s + i);
    ushort4 o;
    o.x = f2bf(f.x); o.y = f2bf(f.y); o.z = f2bf(f.z); o.w = f2bf(f.w);
    *(ushort4*)(d + i) = o;
}

// ---------------- mask (B,L,L) int32 -> bitmask ----------------
__global__ __launch_bounds__(256) void k_mask(
        const int* __restrict__ mask, unsigned long long* __restrict__ bits) {
    int tid = blockIdx.x * 256 + threadIdx.x;
    unsigned long long w = __ballot(mask[tid] != 0);
    if ((threadIdx.x & 63) == 0) bits[tid >> 6] = w;
}

// ---------------- LayerNorm -> bf16 (q,k,v via blockIdx.y) ----------------
__global__ __launch_bounds__(256) void k_ln(
        const float* __restrict__ q, const float* __restrict__ k, const float* __restrict__ v,
        const float* __restrict__ gq, const float* __restrict__ bq,
        const float* __restrict__ gk, const float* __restrict__ bk,
        const float* __restrict__ gv, const float* __restrict__ bv,
        unsigned short* __restrict__ xn) {
    int which = blockIdx.y;
    const float* x = which==0?q: which==1?k: v;
    const float* g = which==0?gq: which==1?gk: gv;
    const float* be = which==0?bq: which==1?bk: bv;
    unsigned short* o = xn + (size_t)which * ((size_t)BB*LL*DD);
    int row = blockIdx.x;
    int t = threadIdx.x;
    const float* xr = x + (size_t)row * DD;
    float4 xv = *(const float4*)(xr + t*4);
    float s  = xv.x + xv.y + xv.z + xv.w;
    float s2 = xv.x*xv.x + xv.y*xv.y + xv.z*xv.z + xv.w*xv.w;
    #pragma unroll
    for (int off = 32; off > 0; off >>= 1) {
        s  += __shfl_down(s, off);
        s2 += __shfl_down(s2, off);
    }
    __shared__ float red[8];
    if ((t & 63) == 0) { red[t>>6] = s; red[4 + (t>>6)] = s2; }
    __syncthreads();
    s  = red[0]+red[1]+red[2]+red[3];
    s2 = red[4]+red[5]+red[6]+red[7];
    float mu  = s * (1.0f/DD);
    float var = s2 * (1.0f/DD) - mu*mu;
    float rs  = rsqrtf(var + 1e-5f);
    float4 gg = *(const float4*)(g + t*4);
    float4 bb = *(const float4*)(be + t*4);
    ushort4 ov;
    ov.x = f2bf((xv.x-mu)*rs*gg.x + bb.x);
    ov.y = f2bf((xv.y-mu)*rs*gg.y + bb.y);
    ov.z = f2bf((xv.z-mu)*rs*gg.z + bb.z);
    ov.w = f2bf((xv.w-mu)*rs*gg.w + bb.w);
    *(ushort4*)(o + (size_t)row*DD + t*4) = ov;
}

// ---------------- GEMM body: C[m][n] = sum_k A[m][k]*W[n][k]  (M=4096,N=1024,K=1024)
// BK=64, padded LDS stride 72, 8 MFMA per barrier pair.
// mode 0: bf16 out [b,h,l,dk] (scaled)   mode 1: bf16 out [b,h,dk,l]   mode 2: fp32 out + resid
__device__ __forceinline__ void gemm_body(
        const unsigned short* __restrict__ A, const unsigned short* __restrict__ W,
        void* __restrict__ Cout, const float* __restrict__ resid, int mode, float scale) {
    __shared__ unsigned short As[64][72];
    __shared__ unsigned short Bs[64][72];
    int m0 = blockIdx.x * 64;
    int n0 = blockIdx.y * 64;
    int t = threadIdx.x;
    int lane = t & 63, wv = t >> 6;
    int quad = lane >> 4, l16 = lane & 15;
    f32x4 acc[4];
    #pragma unroll
    for (int i = 0; i < 4; ++i) acc[i] = (f32x4){0.f,0.f,0.f,0.f};
    int srow = t >> 2;
    int scol = (t & 3) * 16;
    for (int kc = 0; kc < 16; ++kc) {
        int k0 = kc * 64;
        const unsigned short* Ap = A + (size_t)(m0+srow)*DD + k0 + scol;
        const unsigned short* Wp = W + (size_t)(n0+srow)*DD + k0 + scol;
        short8 a0 = *(const short8*)(Ap);
        short8 a1 = *(const short8*)(Ap + 8);
        short8 b0 = *(const short8*)(Wp);
        short8 b1 = *(const short8*)(Wp + 8);
        *(short8*)(&As[srow][scol])   = a0;
        *(short8*)(&As[srow][scol+8]) = a1;
        *(short8*)(&Bs[srow][scol])   = b0;
        *(short8*)(&Bs[srow][scol+8]) = b1;
        __syncthreads();
        short8 af0 = *(const short8*)(&As[wv*16 + l16][quad*8]);
        short8 af1 = *(const short8*)(&As[wv*16 + l16][32 + quad*8]);
        #pragma unroll
        for (int nt = 0; nt < 4; ++nt) {
            short8 bf0 = *(const short8*)(&Bs[nt*16 + l16][quad*8]);
            short8 bf1 = *(const short8*)(&Bs[nt*16 + l16][32 + quad*8]);
            acc[nt] = __builtin_amdgcn_mfma_f32_16x16x32_bf16(af0, bf0, acc[nt], 0, 0, 0);
            acc[nt] = __builtin_amdgcn_mfma_f32_16x16x32_bf16(af1, bf1, acc[nt], 0, 0, 0);
        }
        __syncthreads();
    }
    #pragma unroll
    for (int nt = 0; nt < 4; ++nt) {
        #pragma unroll
        for (int r = 0; r < 4; ++r) {
            int m = m0 + wv*16 + quad*4 + r;
            int n = n0 + nt*16 + l16;
            float val = acc[nt][r];
            if (mode == 2) {
                ((float*)Cout)[(size_t)m*DD + n] = val + resid[(size_t)m*DD + n];
            } else {
                int b = m >> 11, l = m & 2047, h = n >> 6, dk = n & 63;
                unsigned short ov = f2bf(val * scale);
                if (mode == 0)
                    ((unsigned short*)Cout)[((size_t)(b*HH+h)*LL + l)*DKK + dk] = ov;
                else
                    ((unsigned short*)Cout)[((size_t)(b*HH+h)*DKK + dk)*LL + l] = ov;
            }
        }
    }
}

// three projection GEMMs in one launch (z = 0:q, 1:k, 2:v)
__global__ __launch_bounds__(256) void k_gemm3(
        const unsigned short* __restrict__ xn, const unsigned short* __restrict__ Wb,
        unsigned short* __restrict__ qh, unsigned short* __restrict__ kh,
        unsigned short* __restrict__ vT) {
    int z = blockIdx.z;
    const unsigned short* A = xn + (size_t)z * ((size_t)BB*LL*DD);
    const unsigned short* W = Wb + (size_t)z * (DD*DD);
    void* out = (z==0) ? (void*)qh : (z==1) ? (void*)kh : (void*)vT;
    int mode = (z==2) ? 1 : 0;
    float scale = (z==0) ? 0.125f : 1.0f;   // fold 1/sqrt(DK) into Q (exact pow2 in bf16)
    gemm_body(A, W, out, nullptr, mode, scale);
}

// final projection + residual
__global__ __launch_bounds__(256) void k_gemmF(
        const unsigned short* __restrict__ AO, const unsigned short* __restrict__ Wf,
        float* __restrict__ out, const float* __restrict__ resid) {
    gemm_body(AO, Wf, out, resid, 2, 1.0f);
}

// ---------------- fused attention ----------------
// 1D grid of 2048 blocks, XCD-swizzled so all 64 q-tiles of one bh stay on one XCD
// (K/V/Q fetched once per XCD instead of 8x). 32 q-rows per block, K split across
// wave pairs -> 8 blocks/CU -> 32 waves/CU. qh pre-scaled by 0.125.
__global__ __launch_bounds__(256, 8) void k_attn(
        const unsigned short* __restrict__ qh, const unsigned short* __restrict__ kh,
        const unsigned short* __restrict__ vT, const unsigned int* __restrict__ mbits,
        float* __restrict__ attn, unsigned short* __restrict__ AO) {
    // bijective XCD swizzle: nwg=2048, 8 XCDs, 256 logical blocks (=4 bh) per XCD
    int flat = blockIdx.x;
    int swz = (flat & 7) * 256 + (flat >> 3);
    int qt = swz & 63;     // 0..63
    int bh = swz >> 6;     // 0..31
    int b = bh >> 4, h = bh & 15;
    int t = threadIdx.x, lane = t & 63, wv = t >> 6;
    int qg = wv >> 1;        // q-row group (0,1)
    int half = wv & 1;       // K-half (0,1)
    int quad = lane >> 4, l16 = lane & 15;
    int q0 = qt*32 + qg*16;
    int kt0 = half*16;       // 16 kt-tiles of 64 per wave
    const unsigned short* Qb = qh + (size_t)bh * LL * DKK;
    const unsigned short* Kb = kh + (size_t)bh * LL * DKK;
    const unsigned short* Vb = vT + (size_t)bh * DKK * LL;

    __shared__ unsigned short Pl[4][16][72];   // per-wave P tile (no barriers needed)
    __shared__ float ML[2][2][16][2];          // [qg][half][row][m,l]
    __shared__ float Ob[2][16][68];            // O partial from half==1 (padded)

    short8 qf0 = *(const short8*)(Qb + (size_t)(q0 + l16)*DKK + quad*8);
    short8 qf1 = *(const short8*)(Qb + (size_t)(q0 + l16)*DKK + 32 + quad*8);

    float mloc[4], lloc[4];
    #pragma unroll
    for (int r = 0; r < 4; ++r) { mloc[r] = -1e30f; lloc[r] = 0.f; }

    // ---- pass 1: per-lane online (m,l) over this wave's K-half ----
    for (int kt = kt0; kt < kt0 + 16; ++kt) {
        float s[4][4];
        #pragma unroll
        for (int nt = 0; nt < 4; ++nt) {
            const unsigned short* Kp = Kb + (size_t)(kt*64 + nt*16 + l16)*DKK;
            short8 kf0 = *(const short8*)(Kp + quad*8);
            short8 kf1 = *(const short8*)(Kp + 32 + quad*8);
            f32x4 c = (f32x4){0.f,0.f,0.f,0.f};
            c = __builtin_amdgcn_mfma_f32_16x16x32_bf16(qf0, kf0, c, 0, 0, 0);
            c = __builtin_amdgcn_mfma_f32_16x16x32_bf16(qf1, kf1, c, 0, 0, 0);
            #pragma unroll
            for (int r = 0; r < 4; ++r) s[nt][r] = c[r];
        }
        #pragma unroll
        for (int r = 0; r < 4; ++r) {
            int row = q0 + quad*4 + r;
            size_t wb = ((size_t)b*LL + row)*64 + kt*2;
            unsigned int w0 = mbits[wb], w1 = mbits[wb+1];
            #pragma unroll
            for (int nt = 0; nt < 4; ++nt) {
                unsigned int w = (nt < 2) ? w0 : w1;
                if (!((w >> (((nt&1)<<4) + l16)) & 1u)) s[nt][r] = -1e30f;
            }
            float smax = fmaxf(fmaxf(s[0][r], s[1][r]), fmaxf(s[2][r], s[3][r]));
            float mn = fmaxf(mloc[r], smax);
            float corr = __expf(mloc[r] - mn);
            float ps = __expf(s[0][r]-mn) + __expf(s[1][r]-mn)
                     + __expf(s[2][r]-mn) + __expf(s[3][r]-mn);
            lloc[r] = lloc[r]*corr + ps;
            mloc[r] = mn;
        }
    }
    // single cross-lane merge (16 lanes sharing a row, bits 0..3 of lane)
    #pragma unroll
    for (int r = 0; r < 4; ++r) {
        #pragma unroll
        for (int off = 1; off < 16; off <<= 1) {
            float mo = __shfl_xor(mloc[r], off);
            float lo = __shfl_xor(lloc[r], off);
            float mn = fmaxf(mloc[r], mo);
            lloc[r] = lloc[r]*__expf(mloc[r]-mn) + lo*__expf(mo-mn);
            mloc[r] = mn;
        }
    }
    if (l16 == 0) {
        #pragma unroll
        for (int r = 0; r < 4; ++r) {
            ML[qg][half][quad*4+r][0] = mloc[r];
            ML[qg][half][quad*4+r][1] = lloc[r];
        }
    }
    __syncthreads();
    float mrow[4], rinv[4];
    #pragma unroll
    for (int r = 0; r < 4; ++r) {
        float mo = ML[qg][half^1][quad*4+r][0];
        float lo = ML[qg][half^1][quad*4+r][1];
        float mn = fmaxf(mloc[r], mo);
        float lf = lloc[r]*__expf(mloc[r]-mn) + lo*__expf(mo-mn);
        mrow[r] = mn;
        rinv[r] = 1.f / lf;
    }

    // ---- pass 2: recompute, write attn (plain stores -> L2 merges lines), partial O ----
    f32x4 oacc[4];
    #pragma unroll
    for (int i = 0; i < 4; ++i) oacc[i] = (f32x4){0.f,0.f,0.f,0.f};
    float* attn_b = attn + (size_t)bh * LL * LL;

    for (int kt = kt0; kt < kt0 + 16; ++kt) {
        #pragma unroll
        for (int nt = 0; nt < 4; ++nt) {
            const unsigned short* Kp = Kb + (size_t)(kt*64 + nt*16 + l16)*DKK;
            short8 kf0 = *(const short8*)(Kp + quad*8);
            short8 kf1 = *(const short8*)(Kp + 32 + quad*8);
            f32x4 c = (f32x4){0.f,0.f,0.f,0.f};
            c = __builtin_amdgcn_mfma_f32_16x16x32_bf16(qf0, kf0, c, 0, 0, 0);
            c = __builtin_amdgcn_mfma_f32_16x16x32_bf16(qf1, kf1, c, 0, 0, 0);
            #pragma unroll
            for (int r = 0; r < 4; ++r) {
                int row = q0 + quad*4 + r;
                float sv = c[r];
                size_t wb = ((size_t)b*LL + row)*64 + kt*2 + (nt>>1);
                unsigned int w = mbits[wb];
                int bit = (w >> (((nt&1)<<4) + l16)) & 1;
                float p = bit ? __expf(sv - mrow[r]) * rinv[r] : 0.f;
                attn_b[(size_t)row*LL + kt*64 + nt*16 + l16] = p;
                Pl[wv][quad*4 + r][nt*16 + l16] = f2bf(p);
            }
        }
        // intra-wave LDS write->read: ordering guaranteed within the wave, no barrier
        #pragma unroll
        for (int c2 = 0; c2 < 2; ++c2) {
            short8 pf = *(const short8*)(&Pl[wv][l16][c2*32 + quad*8]);
            #pragma unroll
            for (int dt = 0; dt < 4; ++dt) {
                const unsigned short* Vp = Vb + (size_t)(dt*16 + l16)*LL + kt*64 + c2*32 + quad*8;
                short8 vf = *(const short8*)(Vp);
                oacc[dt] = __builtin_amdgcn_mfma_f32_16x16x32_bf16(pf, vf, oacc[dt], 0, 0, 0);
            }
        }
    }

    // ---- merge partial O across the K-half wave pair ----
    if (half == 1) {
        #pragma unroll
        for (int dt = 0; dt < 4; ++dt)
            #pragma unroll
            for (int r = 0; r < 4; ++r)
                Ob[qg][quad*4+r][dt*16+l16] = oacc[dt][r];
    }
    __syncthreads();
    if (half == 0) {
        #pragma unroll
        for (int dt = 0; dt < 4; ++dt) {
            #pragma unroll
            for (int r = 0; r < 4; ++r) {
                int row = q0 + quad*4 + r;
                size_t m = (size_t)b*LL + row;
                float o = oacc[dt][r] + Ob[qg][quad*4+r][dt*16+l16];
                AO[m*DD + h*DKK + dt*16 + l16] = f2bf(o);
            }
        }
    }
}

extern "C" void kernel_launch(void* const* d_in, const int* in_sizes, int n_in,
                              void* d_out, int out_size, void* d_ws, size_t ws_size,
                              hipStream_t stream) {
    const float* q  = (const float*)d_in[0];
    const float* k  = (const float*)d_in[1];
    const float* v  = (const float*)d_in[2];
    const int* mask = (const int*)d_in[3];
    const float* gq = (const float*)d_in[4];
    const float* bq = (const float*)d_in[5];
    const float* gk = (const float*)d_in[6];
    const float* bk = (const float*)d_in[7];
    const float* gv = (const float*)d_in[8];
    const float* bv = (const float*)d_in[9];
    const float* Wq = (const float*)d_in[10];
    const float* Wk = (const float*)d_in[11];
    const float* Wv = (const float*)d_in[12];
    const float* Wfc = (const float*)d_in[13];

    // workspace layout (ushort elements)
    unsigned short* Wb = (unsigned short*)d_ws;        // 4 x 1M bf16          (8 MB)
    unsigned short* xn = Wb + (size_t)4*DD*DD;         // 3 x 4.19M bf16       (24 MB)
    unsigned short* qh = xn + (size_t)3*BB*LL*DD;      // 4.19M bf16           (8 MB)
    unsigned short* kh = qh + (size_t)BB*LL*DD;        // 4.19M bf16           (8 MB)
    unsigned short* vT = kh + (size_t)BB*LL*DD;        // 4.19M bf16           (8 MB)
    unsigned int* mb  = (unsigned int*)(vT + (size_t)BB*LL*DD);  // 1.05 MB
    unsigned short* AO = xn;                           // alias: xn dead after projections

    float* out_main = (float*)d_out;                       // (B,L,D)
    float* out_attn = out_main + (size_t)BB*LL*DD;         // (B,H,L,L)

    dim3 blk(256);
    k_convw<<<dim3((DD*DD)/1024, 4), blk, 0, stream>>>(Wq, Wk, Wv, Wfc, Wb);
    k_mask<<<dim3((BB*LL*LL)/256), blk, 0, stream>>>(mask, (unsigned long long*)mb);
    k_ln<<<dim3(BB*LL, 3), blk, 0, stream>>>(q, k, v, gq, bq, gk, bk, gv, bv, xn);

    // projections: qh (scaled by 1/8) / kh row-major per head, vh transposed — one launch
    k_gemm3<<<dim3(64, 16, 3), blk, 0, stream>>>(xn, Wb, qh, kh, vT);

    k_attn<<<dim3(2048), blk, 0, stream>>>(qh, kh, vT, mb, out_attn, AO);

    // final projection + residual
    k_gemmF<<<dim3(64, 16), blk, 0, stream>>>(AO, Wb + (size_t)3*DD*DD, out_main, q);
}

// Round 3
// 1101.755 us; speedup vs baseline: 1.1482x; 1.1482x over previous
//
#include <hip/hip_runtime.h>
#include <stdint.h>

#define BB 2
#define LL 2048
#define DD 1024
#define HH 16
#define DKK 64

typedef __attribute__((ext_vector_type(8))) short short8;
typedef __attribute__((ext_vector_type(4))) float f32x4;

__device__ __forceinline__ unsigned short f2bf(float x) {
    union { float f; unsigned int u; } v; v.f = x;
    unsigned int r = v.u + 0x7FFFu + ((v.u >> 16) & 1u);
    return (unsigned short)(r >> 16);
}
__device__ __forceinline__ float bf2f(unsigned short b) {
    union { unsigned int u; float f; } v; v.u = ((unsigned int)b) << 16;
    return v.f;
}

// ---------------- W fp32 -> bf16 ----------------
__global__ __launch_bounds__(256) void k_convw(
        const float* __restrict__ w0, const float* __restrict__ w1,
        const float* __restrict__ w2, const float* __restrict__ w3,
        unsigned short* __restrict__ dst) {
    int which = blockIdx.y;
    const float* s = which==0?w0: which==1?w1: which==2?w2: w3;
    unsigned short* d = dst + (size_t)which * (DD*DD);
    int i = (blockIdx.x * 256 + threadIdx.x) * 4;
    float4 f = *(const float4*)(s + i);
    ushort4 o;
    o.x = f2bf(f.x); o.y = f2bf(f.y); o.z = f2bf(f.z); o.w = f2bf(f.w);
    *(ushort4*)(d + i) = o;
}

// ---------------- mask (B,L,L) int32 -> bitmask ----------------
__global__ __launch_bounds__(256) void k_mask(
        const int* __restrict__ mask, unsigned long long* __restrict__ bits) {
    int tid = blockIdx.x * 256 + threadIdx.x;
    unsigned long long w = __ballot(mask[tid] != 0);
    if ((threadIdx.x & 63) == 0) bits[tid >> 6] = w;
}

// ---------------- LayerNorm -> bf16 (q,k,v via blockIdx.y) ----------------
__global__ __launch_bounds__(256) void k_ln(
        const float* __restrict__ q, const float* __restrict__ k, const float* __restrict__ v,
        const float* __restrict__ gq, const float* __restrict__ bq,
        const float* __restrict__ gk, const float* __restrict__ bk,
        const float* __restrict__ gv, const float* __restrict__ bv,
        unsigned short* __restrict__ xn) {
    int which = blockIdx.y;
    const float* x = which==0?q: which==1?k: v;
    const float* g = which==0?gq: which==1?gk: gv;
    const float* be = which==0?bq: which==1?bk: bv;
    unsigned short* o = xn + (size_t)which * ((size_t)BB*LL*DD);
    int row = blockIdx.x;
    int t = threadIdx.x;
    const float* xr = x + (size_t)row * DD;
    float4 xv = *(const float4*)(xr + t*4);
    float s  = xv.x + xv.y + xv.z + xv.w;
    float s2 = xv.x*xv.x + xv.y*xv.y + xv.z*xv.z + xv.w*xv.w;
    #pragma unroll
    for (int off = 32; off > 0; off >>= 1) {
        s  += __shfl_down(s, off);
        s2 += __shfl_down(s2, off);
    }
    __shared__ float red[8];
    if ((t & 63) == 0) { red[t>>6] = s; red[4 + (t>>6)] = s2; }
    __syncthreads();
    s  = red[0]+red[1]+red[2]+red[3];
    s2 = red[4]+red[5]+red[6]+red[7];
    float mu  = s * (1.0f/DD);
    float var = s2 * (1.0f/DD) - mu*mu;
    float rs  = rsqrtf(var + 1e-5f);
    float4 gg = *(const float4*)(g + t*4);
    float4 bb = *(const float4*)(be + t*4);
    ushort4 ov;
    ov.x = f2bf((xv.x-mu)*rs*gg.x + bb.x);
    ov.y = f2bf((xv.y-mu)*rs*gg.y + bb.y);
    ov.z = f2bf((xv.z-mu)*rs*gg.z + bb.z);
    ov.w = f2bf((xv.w-mu)*rs*gg.w + bb.w);
    *(ushort4*)(o + (size_t)row*DD + t*4) = ov;
}

// ---------------- GEMM body: C[m][n] = sum_k A[m][k]*W[n][k]  (M=4096,N=1024,K=1024)
// BK=64, LDS stride 76 (76*2/4 = 38 dwords == 6 mod 32 -> ~2-way, conflict-free fragment reads).
// mode 0: bf16 [b,h,l,dk] (scaled)  mode 1: bf16 [b,h,dk,l]  mode 2: fp32 + resid
// Modes 0/1 stage the C-tile in LDS and write full 128B lines.
__device__ __forceinline__ void gemm_body(
        const unsigned short* __restrict__ A, const unsigned short* __restrict__ W,
        void* __restrict__ Cout, const float* __restrict__ resid, int mode, float scale) {
    __shared__ unsigned short As[64][76];
    __shared__ unsigned short Bs[64][76];
    int m0 = blockIdx.x * 64;
    int n0 = blockIdx.y * 64;
    int t = threadIdx.x;
    int lane = t & 63, wv = t >> 6;
    int quad = lane >> 4, l16 = lane & 15;
    f32x4 acc[4];
    #pragma unroll
    for (int i = 0; i < 4; ++i) acc[i] = (f32x4){0.f,0.f,0.f,0.f};
    int srow = t >> 2;
    int scol = (t & 3) * 16;
    for (int kc = 0; kc < 16; ++kc) {
        int k0 = kc * 64;
        const unsigned short* Ap = A + (size_t)(m0+srow)*DD + k0 + scol;
        const unsigned short* Wp = W + (size_t)(n0+srow)*DD + k0 + scol;
        short8 a0 = *(const short8*)(Ap);
        short8 a1 = *(const short8*)(Ap + 8);
        short8 b0 = *(const short8*)(Wp);
        short8 b1 = *(const short8*)(Wp + 8);
        *(short8*)(&As[srow][scol])   = a0;
        *(short8*)(&As[srow][scol+8]) = a1;
        *(short8*)(&Bs[srow][scol])   = b0;
        *(short8*)(&Bs[srow][scol+8]) = b1;
        __syncthreads();
        short8 af0 = *(const short8*)(&As[wv*16 + l16][quad*8]);
        short8 af1 = *(const short8*)(&As[wv*16 + l16][32 + quad*8]);
        #pragma unroll
        for (int nt = 0; nt < 4; ++nt) {
            short8 bf0 = *(const short8*)(&Bs[nt*16 + l16][quad*8]);
            short8 bf1 = *(const short8*)(&Bs[nt*16 + l16][32 + quad*8]);
            acc[nt] = __builtin_amdgcn_mfma_f32_16x16x32_bf16(af0, bf0, acc[nt], 0, 0, 0);
            acc[nt] = __builtin_amdgcn_mfma_f32_16x16x32_bf16(af1, bf1, acc[nt], 0, 0, 0);
        }
        __syncthreads();
    }
    if (mode == 2) {
        #pragma unroll
        for (int nt = 0; nt < 4; ++nt) {
            #pragma unroll
            for (int r = 0; r < 4; ++r) {
                int m = m0 + wv*16 + quad*4 + r;
                int n = n0 + nt*16 + l16;
                ((float*)Cout)[(size_t)m*DD + n] = acc[nt][r] + resid[(size_t)m*DD + n];
            }
        }
        return;
    }
    // stage bf16 C-tile in As (dead after final barrier of the kc loop)
    unsigned short (*Ts)[76] = As;
    #pragma unroll
    for (int nt = 0; nt < 4; ++nt) {
        #pragma unroll
        for (int r = 0; r < 4; ++r) {
            unsigned short ov = f2bf(acc[nt][r] * scale);
            int ml = wv*16 + quad*4 + r;   // m-local
            int nl = nt*16 + l16;          // n-local
            if (mode == 0) Ts[ml][nl] = ov;
            else           Ts[nl][ml] = ov;
        }
    }
    __syncthreads();
    // write 64x64 bf16 tile as full 128B lines: 8 lanes/row x 16B, 32 rows/pass
    int b = m0 >> 11, lbase = m0 & 2047, h = n0 >> 6;
    #pragma unroll
    for (int ps = 0; ps < 2; ++ps) {
        int rr = ps*32 + (t >> 3);
        int cc = (t & 7) * 8;
        short8 val = *(const short8*)(&Ts[rr][cc]);
        unsigned short* dst;
        if (mode == 0)   // rr = m-local, cc = dk
            dst = (unsigned short*)Cout + ((size_t)(b*HH + h)*LL + (lbase + rr))*DKK + cc;
        else             // rr = dk, cc = l-local
            dst = (unsigned short*)Cout + ((size_t)(b*HH + h)*DKK + rr)*LL + lbase + cc;
        *(short8*)dst = val;
    }
}

// three projection GEMMs in one launch (z = 0:q, 1:k, 2:v)
__global__ __launch_bounds__(256) void k_gemm3(
        const unsigned short* __restrict__ xn, const unsigned short* __restrict__ Wb,
        unsigned short* __restrict__ qh, unsigned short* __restrict__ kh,
        unsigned short* __restrict__ vT) {
    int z = blockIdx.z;
    const unsigned short* A = xn + (size_t)z * ((size_t)BB*LL*DD);
    const unsigned short* W = Wb + (size_t)z * (DD*DD);
    void* out = (z==0) ? (void*)qh : (z==1) ? (void*)kh : (void*)vT;
    int mode = (z==2) ? 1 : 0;
    float scale = (z==0) ? 0.125f : 1.0f;   // fold 1/sqrt(DK) into Q (exact pow2 in bf16)
    gemm_body(A, W, out, nullptr, mode, scale);
}

// final projection + residual
__global__ __launch_bounds__(256) void k_gemmF(
        const unsigned short* __restrict__ AO, const unsigned short* __restrict__ Wf,
        float* __restrict__ out, const float* __restrict__ resid) {
    gemm_body(AO, Wf, out, resid, 2, 1.0f);
}

// ---------------- fused attention ----------------
// 2048 blocks XCD-swizzled (4 bh per XCD -> K/V L2-resident). 32 q-rows/block,
// K split across wave pairs -> 8 blocks/CU -> 32 waves/CU. qh pre-scaled by 0.125.
// attn written from the LDS P-tile as full 128B lines (one tight burst per kt).
__global__ __launch_bounds__(256, 8) void k_attn(
        const unsigned short* __restrict__ qh, const unsigned short* __restrict__ kh,
        const unsigned short* __restrict__ vT, const unsigned int* __restrict__ mbits,
        float* __restrict__ attn, unsigned short* __restrict__ AO) {
    int flat = blockIdx.x;
    int swz = (flat & 7) * 256 + (flat >> 3);
    int qt = swz & 63;     // 0..63
    int bh = swz >> 6;     // 0..31
    int b = bh >> 4, h = bh & 15;
    int t = threadIdx.x, lane = t & 63, wv = t >> 6;
    int qg = wv >> 1;        // q-row group (0,1)
    int half = wv & 1;       // K-half (0,1)
    int quad = lane >> 4, l16 = lane & 15;
    int q0 = qt*32 + qg*16;
    int kt0 = half*16;       // 16 kt-tiles of 64 per wave
    const unsigned short* Qb = qh + (size_t)bh * LL * DKK;
    const unsigned short* Kb = kh + (size_t)bh * LL * DKK;
    const unsigned short* Vb = vT + (size_t)bh * DKK * LL;

    __shared__ unsigned short Pl[4][16][76];   // per-wave P tile (stride 76: ~2-way banks)
    __shared__ float ML[2][2][16][2];          // [qg][half][row][m,l]
    __shared__ float Ob[2][16][68];            // O partial from half==1 (padded)

    short8 qf0 = *(const short8*)(Qb + (size_t)(q0 + l16)*DKK + quad*8);
    short8 qf1 = *(const short8*)(Qb + (size_t)(q0 + l16)*DKK + 32 + quad*8);

    float mloc[4], lloc[4];
    #pragma unroll
    for (int r = 0; r < 4; ++r) { mloc[r] = -1e30f; lloc[r] = 0.f; }

    // ---- pass 1: per-lane online (m,l) over this wave's K-half ----
    for (int kt = kt0; kt < kt0 + 16; ++kt) {
        float s[4][4];
        #pragma unroll
        for (int nt = 0; nt < 4; ++nt) {
            const unsigned short* Kp = Kb + (size_t)(kt*64 + nt*16 + l16)*DKK;
            short8 kf0 = *(const short8*)(Kp + quad*8);
            short8 kf1 = *(const short8*)(Kp + 32 + quad*8);
            f32x4 c = (f32x4){0.f,0.f,0.f,0.f};
            c = __builtin_amdgcn_mfma_f32_16x16x32_bf16(qf0, kf0, c, 0, 0, 0);
            c = __builtin_amdgcn_mfma_f32_16x16x32_bf16(qf1, kf1, c, 0, 0, 0);
            #pragma unroll
            for (int r = 0; r < 4; ++r) s[nt][r] = c[r];
        }
        #pragma unroll
        for (int r = 0; r < 4; ++r) {
            int row = q0 + quad*4 + r;
            size_t wb = ((size_t)b*LL + row)*64 + kt*2;
            unsigned int w0 = mbits[wb], w1 = mbits[wb+1];
            #pragma unroll
            for (int nt = 0; nt < 4; ++nt) {
                unsigned int w = (nt < 2) ? w0 : w1;
                if (!((w >> (((nt&1)<<4) + l16)) & 1u)) s[nt][r] = -1e30f;
            }
            float smax = fmaxf(fmaxf(s[0][r], s[1][r]), fmaxf(s[2][r], s[3][r]));
            float mn = fmaxf(mloc[r], smax);
            float corr = __expf(mloc[r] - mn);
            float ps = __expf(s[0][r]-mn) + __expf(s[1][r]-mn)
                     + __expf(s[2][r]-mn) + __expf(s[3][r]-mn);
            lloc[r] = lloc[r]*corr + ps;
            mloc[r] = mn;
        }
    }
    // single cross-lane merge (16 lanes sharing a row)
    #pragma unroll
    for (int r = 0; r < 4; ++r) {
        #pragma unroll
        for (int off = 1; off < 16; off <<= 1) {
            float mo = __shfl_xor(mloc[r], off);
            float lo = __shfl_xor(lloc[r], off);
            float mn = fmaxf(mloc[r], mo);
            lloc[r] = lloc[r]*__expf(mloc[r]-mn) + lo*__expf(mo-mn);
            mloc[r] = mn;
        }
    }
    if (l16 == 0) {
        #pragma unroll
        for (int r = 0; r < 4; ++r) {
            ML[qg][half][quad*4+r][0] = mloc[r];
            ML[qg][half][quad*4+r][1] = lloc[r];
        }
    }
    __syncthreads();
    float mrow[4], rinv[4];
    #pragma unroll
    for (int r = 0; r < 4; ++r) {
        float mo = ML[qg][half^1][quad*4+r][0];
        float lo = ML[qg][half^1][quad*4+r][1];
        float mn = fmaxf(mloc[r], mo);
        float lf = lloc[r]*__expf(mloc[r]-mn) + lo*__expf(mo-mn);
        mrow[r] = mn;
        rinv[r] = 1.f / lf;
    }

    // ---- pass 2: recompute, stage P in LDS, burst-store attn as full lines, PV ----
    f32x4 oacc[4];
    #pragma unroll
    for (int i = 0; i < 4; ++i) oacc[i] = (f32x4){0.f,0.f,0.f,0.f};
    float* attn_b = attn + (size_t)bh * LL * LL;

    for (int kt = kt0; kt < kt0 + 16; ++kt) {
        #pragma unroll
        for (int nt = 0; nt < 4; ++nt) {
            const unsigned short* Kp = Kb + (size_t)(kt*64 + nt*16 + l16)*DKK;
            short8 kf0 = *(const short8*)(Kp + quad*8);
            short8 kf1 = *(const short8*)(Kp + 32 + quad*8);
            f32x4 c = (f32x4){0.f,0.f,0.f,0.f};
            c = __builtin_amdgcn_mfma_f32_16x16x32_bf16(qf0, kf0, c, 0, 0, 0);
            c = __builtin_amdgcn_mfma_f32_16x16x32_bf16(qf1, kf1, c, 0, 0, 0);
            #pragma unroll
            for (int r = 0; r < 4; ++r) {
                float sv = c[r];
                int row = q0 + quad*4 + r;
                size_t wb = ((size_t)b*LL + row)*64 + kt*2 + (nt>>1);
                unsigned int w = mbits[wb];
                int bit = (w >> (((nt&1)<<4) + l16)) & 1;
                float p = bit ? __expf(sv - mrow[r]) * rinv[r] : 0.f;
                Pl[wv][quad*4 + r][nt*16 + l16] = f2bf(p);
            }
        }
        // burst: write this wave's 16x64 P tile to attn as f32, full 128B lines.
        // lane -> row = lane>>3 (+8*ri), 8 lanes/row x 4 floats = 128B per line.
        {
            int rr8 = lane >> 3, cc = (lane & 7) * 4;
            #pragma unroll
            for (int ri = 0; ri < 2; ++ri) {
                int rr = ri*8 + rr8;
                float* drow = attn_b + (size_t)(q0 + rr)*LL + kt*64;
                #pragma unroll
                for (int ci = 0; ci < 2; ++ci) {
                    ushort4 pv4 = *(const ushort4*)(&Pl[wv][rr][ci*32 + cc]);
                    f32x4 fo;
                    fo[0] = bf2f(pv4.x); fo[1] = bf2f(pv4.y);
                    fo[2] = bf2f(pv4.z); fo[3] = bf2f(pv4.w);
                    *(f32x4*)(drow + ci*32 + cc) = fo;
                }
            }
        }
        // PV: intra-wave LDS write->read, no barrier needed
        #pragma unroll
        for (int c2 = 0; c2 < 2; ++c2) {
            short8 pf = *(const short8*)(&Pl[wv][l16][c2*32 + quad*8]);
            #pragma unroll
            for (int dt = 0; dt < 4; ++dt) {
                const unsigned short* Vp = Vb + (size_t)(dt*16 + l16)*LL + kt*64 + c2*32 + quad*8;
                short8 vf = *(const short8*)(Vp);
                oacc[dt] = __builtin_amdgcn_mfma_f32_16x16x32_bf16(pf, vf, oacc[dt], 0, 0, 0);
            }
        }
    }

    // ---- merge partial O across the K-half wave pair ----
    if (half == 1) {
        #pragma unroll
        for (int dt = 0; dt < 4; ++dt)
            #pragma unroll
            for (int r = 0; r < 4; ++r)
                Ob[qg][quad*4+r][dt*16+l16] = oacc[dt][r];
    }
    __syncthreads();
    if (half == 0) {
        #pragma unroll
        for (int dt = 0; dt < 4; ++dt) {
            #pragma unroll
            for (int r = 0; r < 4; ++r) {
                int row = q0 + quad*4 + r;
                size_t m = (size_t)b*LL + row;
                float o = oacc[dt][r] + Ob[qg][quad*4+r][dt*16+l16];
                AO[m*DD + h*DKK + dt*16 + l16] = f2bf(o);
            }
        }
    }
}

extern "C" void kernel_launch(void* const* d_in, const int* in_sizes, int n_in,
                              void* d_out, int out_size, void* d_ws, size_t ws_size,
                              hipStream_t stream) {
    const float* q  = (const float*)d_in[0];
    const float* k  = (const float*)d_in[1];
    const float* v  = (const float*)d_in[2];
    const int* mask = (const int*)d_in[3];
    const float* gq = (const float*)d_in[4];
    const float* bq = (const float*)d_in[5];
    const float* gk = (const float*)d_in[6];
    const float* bk = (const float*)d_in[7];
    const float* gv = (const float*)d_in[8];
    const float* bv = (const float*)d_in[9];
    const float* Wq = (const float*)d_in[10];
    const float* Wk = (const float*)d_in[11];
    const float* Wv = (const float*)d_in[12];
    const float* Wfc = (const float*)d_in[13];

    // workspace layout (ushort elements)
    unsigned short* Wb = (unsigned short*)d_ws;        // 4 x 1M bf16          (8 MB)
    unsigned short* xn = Wb + (size_t)4*DD*DD;         // 3 x 4.19M bf16       (24 MB)
    unsigned short* qh = xn + (size_t)3*BB*LL*DD;      // 4.19M bf16           (8 MB)
    unsigned short* kh = qh + (size_t)BB*LL*DD;        // 4.19M bf16           (8 MB)
    unsigned short* vT = kh + (size_t)BB*LL*DD;        // 4.19M bf16           (8 MB)
    unsigned int* mb  = (unsigned int*)(vT + (size_t)BB*LL*DD);  // 1.05 MB
    unsigned short* AO = xn;                           // alias: xn dead after projections

    float* out_main = (float*)d_out;                       // (B,L,D)
    float* out_attn = out_main + (size_t)BB*LL*DD;         // (B,H,L,L)

    dim3 blk(256);
    k_convw<<<dim3((DD*DD)/1024, 4), blk, 0, stream>>>(Wq, Wk, Wv, Wfc, Wb);
    k_mask<<<dim3((BB*LL*LL)/256), blk, 0, stream>>>(mask, (unsigned long long*)mb);
    k_ln<<<dim3(BB*LL, 3), blk, 0, stream>>>(q, k, v, gq, bq, gk, bk, gv, bv, xn);

    // projections: qh (scaled by 1/8) / kh row-major per head, vh transposed — one launch
    k_gemm3<<<dim3(64, 16, 3), blk, 0, stream>>>(xn, Wb, qh, kh, vT);

    k_attn<<<dim3(2048), blk, 0, stream>>>(qh, kh, vT, mb, out_attn, AO);

    // final projection + residual
    k_gemmF<<<dim3(64, 16), blk, 0, stream>>>(AO, Wb + (size_t)3*DD*DD, out_main, q);
}

// Round 4
// 826.620 us; speedup vs baseline: 1.5304x; 1.3328x over previous
//
#include <hip/hip_runtime.h>
#include <stdint.h>

#define BB 2
#define LL 2048
#define DD 1024
#define HH 16
#define DKK 64

typedef __attribute__((ext_vector_type(8))) short short8;
typedef __attribute__((ext_vector_type(4))) float f32x4;

__device__ __forceinline__ unsigned short f2bf(float x) {
    union { float f; unsigned int u; } v; v.f = x;
    unsigned int r = v.u + 0x7FFFu + ((v.u >> 16) & 1u);
    return (unsigned short)(r >> 16);
}
__device__ __forceinline__ float bf2f(unsigned short b) {
    union { unsigned int u; float f; } v; v.u = ((unsigned int)b) << 16;
    return v.f;
}

// ---------------- fused prep: convw | mask | layernorm in one launch ----------------
// blocks [0,4096): W fp32->bf16   [4096,36864): mask->bits   [36864,49152): LN->bf16
__global__ __launch_bounds__(256) void k_prep(
        const float* __restrict__ w0, const float* __restrict__ w1,
        const float* __restrict__ w2, const float* __restrict__ w3,
        unsigned short* __restrict__ Wb,
        const int* __restrict__ mask, unsigned long long* __restrict__ bits,
        const float* __restrict__ q, const float* __restrict__ k, const float* __restrict__ v,
        const float* __restrict__ gq, const float* __restrict__ bq,
        const float* __restrict__ gk, const float* __restrict__ bk,
        const float* __restrict__ gv, const float* __restrict__ bv,
        unsigned short* __restrict__ xn) {
    int bid = blockIdx.x, t = threadIdx.x;
    if (bid < 4096) {
        int which = bid >> 10;
        const float* s = which==0?w0: which==1?w1: which==2?w2: w3;
        unsigned short* d = Wb + (size_t)which * (DD*DD);
        int i = ((bid & 1023) * 256 + t) * 4;
        float4 f = *(const float4*)(s + i);
        ushort4 o;
        o.x = f2bf(f.x); o.y = f2bf(f.y); o.z = f2bf(f.z); o.w = f2bf(f.w);
        *(ushort4*)(d + i) = o;
    } else if (bid < 36864) {
        int tid = (bid - 4096) * 256 + t;
        unsigned long long w = __ballot(mask[tid] != 0);
        if ((t & 63) == 0) bits[tid >> 6] = w;
    } else {
        int idx = bid - 36864;
        int which = idx >> 12;          // 0:q 1:k 2:v
        int row = idx & 4095;
        const float* x = which==0?q: which==1?k: v;
        const float* g = which==0?gq: which==1?gk: gv;
        const float* be = which==0?bq: which==1?bk: bv;
        unsigned short* o = xn + (size_t)which * ((size_t)BB*LL*DD);
        const float* xr = x + (size_t)row * DD;
        float4 xv = *(const float4*)(xr + t*4);
        float s  = xv.x + xv.y + xv.z + xv.w;
        float s2 = xv.x*xv.x + xv.y*xv.y + xv.z*xv.z + xv.w*xv.w;
        #pragma unroll
        for (int off = 32; off > 0; off >>= 1) {
            s  += __shfl_down(s, off);
            s2 += __shfl_down(s2, off);
        }
        __shared__ float red[8];
        if ((t & 63) == 0) { red[t>>6] = s; red[4 + (t>>6)] = s2; }
        __syncthreads();
        s  = red[0]+red[1]+red[2]+red[3];
        s2 = red[4]+red[5]+red[6]+red[7];
        float mu  = s * (1.0f/DD);
        float var = s2 * (1.0f/DD) - mu*mu;
        float rs  = rsqrtf(var + 1e-5f);
        float4 gg = *(const float4*)(g + t*4);
        float4 bb = *(const float4*)(be + t*4);
        ushort4 ov;
        ov.x = f2bf((xv.x-mu)*rs*gg.x + bb.x);
        ov.y = f2bf((xv.y-mu)*rs*gg.y + bb.y);
        ov.z = f2bf((xv.z-mu)*rs*gg.z + bb.z);
        ov.w = f2bf((xv.w-mu)*rs*gg.w + bb.w);
        *(ushort4*)(o + (size_t)row*DD + t*4) = ov;
    }
}

// ---------------- GEMM body: C[m][n] = sum_k A[m][k]*W[n][k]  (M=4096,N=1024,K=1024)
// BK=64, LDS stride 76. mode 0: bf16 [b,h,l,dk] (scaled)  mode 1: bf16 [b,h,dk,l]
// mode 2: fp32 + resid.  Modes 0/1 stage the C-tile in LDS, write full 128B lines.
__device__ __forceinline__ void gemm_body(
        const unsigned short* __restrict__ A, const unsigned short* __restrict__ W,
        void* __restrict__ Cout, const float* __restrict__ resid, int mode, float scale,
        int m0, int n0) {
    __shared__ unsigned short As[64][76];
    __shared__ unsigned short Bs[64][76];
    int t = threadIdx.x;
    int lane = t & 63, wv = t >> 6;
    int quad = lane >> 4, l16 = lane & 15;
    f32x4 acc[4];
    #pragma unroll
    for (int i = 0; i < 4; ++i) acc[i] = (f32x4){0.f,0.f,0.f,0.f};
    int srow = t >> 2;
    int scol = (t & 3) * 16;
    for (int kc = 0; kc < 16; ++kc) {
        int k0 = kc * 64;
        const unsigned short* Ap = A + (size_t)(m0+srow)*DD + k0 + scol;
        const unsigned short* Wp = W + (size_t)(n0+srow)*DD + k0 + scol;
        short8 a0 = *(const short8*)(Ap);
        short8 a1 = *(const short8*)(Ap + 8);
        short8 b0 = *(const short8*)(Wp);
        short8 b1 = *(const short8*)(Wp + 8);
        *(short8*)(&As[srow][scol])   = a0;
        *(short8*)(&As[srow][scol+8]) = a1;
        *(short8*)(&Bs[srow][scol])   = b0;
        *(short8*)(&Bs[srow][scol+8]) = b1;
        __syncthreads();
        short8 af0 = *(const short8*)(&As[wv*16 + l16][quad*8]);
        short8 af1 = *(const short8*)(&As[wv*16 + l16][32 + quad*8]);
        #pragma unroll
        for (int nt = 0; nt < 4; ++nt) {
            short8 bf0 = *(const short8*)(&Bs[nt*16 + l16][quad*8]);
            short8 bf1 = *(const short8*)(&Bs[nt*16 + l16][32 + quad*8]);
            acc[nt] = __builtin_amdgcn_mfma_f32_16x16x32_bf16(af0, bf0, acc[nt], 0, 0, 0);
            acc[nt] = __builtin_amdgcn_mfma_f32_16x16x32_bf16(af1, bf1, acc[nt], 0, 0, 0);
        }
        __syncthreads();
    }
    if (mode == 2) {
        #pragma unroll
        for (int nt = 0; nt < 4; ++nt) {
            #pragma unroll
            for (int r = 0; r < 4; ++r) {
                int m = m0 + wv*16 + quad*4 + r;
                int n = n0 + nt*16 + l16;
                ((float*)Cout)[(size_t)m*DD + n] = acc[nt][r] + resid[(size_t)m*DD + n];
            }
        }
        return;
    }
    unsigned short (*Ts)[76] = As;
    #pragma unroll
    for (int nt = 0; nt < 4; ++nt) {
        #pragma unroll
        for (int r = 0; r < 4; ++r) {
            unsigned short ov = f2bf(acc[nt][r] * scale);
            int ml = wv*16 + quad*4 + r;
            int nl = nt*16 + l16;
            if (mode == 0) Ts[ml][nl] = ov;
            else           Ts[nl][ml] = ov;
        }
    }
    __syncthreads();
    int b = m0 >> 11, lbase = m0 & 2047, h = n0 >> 6;
    #pragma unroll
    for (int ps = 0; ps < 2; ++ps) {
        int rr = ps*32 + (t >> 3);
        int cc = (t & 7) * 8;
        short8 val = *(const short8*)(&Ts[rr][cc]);
        unsigned short* dst;
        if (mode == 0)
            dst = (unsigned short*)Cout + ((size_t)(b*HH + h)*LL + (lbase + rr))*DKK + cc;
        else
            dst = (unsigned short*)Cout + ((size_t)(b*HH + h)*DKK + rr)*LL + lbase + cc;
        *(short8*)dst = val;
    }
}

// three projection GEMMs, 1D grid 3072, XCD-chunked, n0 fastest (A-panel L2 reuse)
__global__ __launch_bounds__(256) void k_gemm3(
        const unsigned short* __restrict__ xn, const unsigned short* __restrict__ Wb,
        unsigned short* __restrict__ qh, unsigned short* __restrict__ kh,
        unsigned short* __restrict__ vT) {
    int flat = blockIdx.x;
    int swz = (flat & 7) * 384 + (flat >> 3);
    int z = swz >> 10;
    int rr = swz & 1023;
    int m0 = (rr >> 4) * 64;
    int n0 = (rr & 15) * 64;
    const unsigned short* A = xn + (size_t)z * ((size_t)BB*LL*DD);
    const unsigned short* W = Wb + (size_t)z * (DD*DD);
    void* out = (z==0) ? (void*)qh : (z==1) ? (void*)kh : (void*)vT;
    int mode = (z==2) ? 1 : 0;
    float scale = (z==0) ? 0.125f : 1.0f;   // fold 1/sqrt(DK) into Q
    gemm_body(A, W, out, nullptr, mode, scale, m0, n0);
}

__global__ __launch_bounds__(256) void k_gemmF(
        const unsigned short* __restrict__ AO, const unsigned short* __restrict__ Wf,
        float* __restrict__ out, const float* __restrict__ resid) {
    int flat = blockIdx.x;
    int swz = (flat & 7) * 128 + (flat >> 3);
    int m0 = (swz >> 4) * 64;
    int n0 = (swz & 15) * 64;
    gemm_body(AO, Wf, out, resid, 2, 1.0f, m0, n0);
}

// ---------------- fused attention ----------------
// Block = 64 q-rows x 4 waves in LOCKSTEP over all 32 kt. K/V tiles staged in LDS
// cooperatively (full-line loads; ~20x fewer L1 line-requests than per-wave gather),
// register-prefetch of kt+1 hides global latency under compute. Each wave owns 16
// q-rows over the FULL K range: no cross-wave (m,l)/O merges. Grid 1024, XCD-chunked
// (4 bh per XCD -> K/V L2-resident). qh pre-scaled by 0.125.
__global__ __launch_bounds__(256, 4) void k_attn(
        const unsigned short* __restrict__ qh, const unsigned short* __restrict__ kh,
        const unsigned short* __restrict__ vT, const unsigned int* __restrict__ mbits,
        float* __restrict__ attn, unsigned short* __restrict__ AO) {
    int flat = blockIdx.x;                     // 1024
    int swz = (flat & 7) * 128 + (flat >> 3);  // bijective, 128 blocks/XCD
    int qt = swz & 31;     // 0..31 (64 q-rows each)
    int bh = swz >> 5;     // 0..31
    int b = bh >> 4, h = bh & 15;
    int t = threadIdx.x, lane = t & 63, wv = t >> 6;
    int quad = lane >> 4, l16 = lane & 15;
    int q0 = qt*64 + wv*16;                    // wave's 16 q-rows
    const unsigned short* Qb = qh + (size_t)bh * LL * DKK;
    const unsigned short* Kb = kh + (size_t)bh * LL * DKK;
    const unsigned short* Vb = vT + (size_t)bh * DKK * LL;

    __shared__ unsigned short Ks[64][76];      // k-row x dk
    __shared__ unsigned short Vs[64][76];      // dk x k-col (V^T tile)
    __shared__ unsigned short Pl[4][16][76];   // per-wave P tile

    int srow = t >> 2, scol = (t & 3) * 16;    // staging: 4 threads/row, 32B each

    short8 qf0 = *(const short8*)(Qb + (size_t)(q0 + l16)*DKK + quad*8);
    short8 qf1 = *(const short8*)(Qb + (size_t)(q0 + l16)*DKK + 32 + quad*8);

    // hoisted 32-bit mask row bases
    unsigned int mbase[4];
    #pragma unroll
    for (int r = 0; r < 4; ++r) mbase[r] = (unsigned)((b*LL + q0 + quad*4 + r) * 64);

    float mloc[4], lloc[4];
    #pragma unroll
    for (int r = 0; r < 4; ++r) { mloc[r] = -1e30f; lloc[r] = 0.f; }

    // ---- pass 1: QK^T -> per-lane online (m,l); K staged in LDS, prefetch kt+1 ----
    {
        const unsigned short* kg = Kb + (size_t)srow*DKK + scol;
        short8 ka = *(const short8*)(kg);
        short8 kb2 = *(const short8*)(kg + 8);
        for (int kt = 0; kt < 32; ++kt) {
            __syncthreads();
            *(short8*)(&Ks[srow][scol])   = ka;
            *(short8*)(&Ks[srow][scol+8]) = kb2;
            if (kt < 31) {
                const unsigned short* kn = Kb + (size_t)((kt+1)*64 + srow)*DKK + scol;
                ka = *(const short8*)(kn);
                kb2 = *(const short8*)(kn + 8);
            }
            __syncthreads();
            float s[4][4];
            #pragma unroll
            for (int nt = 0; nt < 4; ++nt) {
                short8 bf0 = *(const short8*)(&Ks[nt*16 + l16][quad*8]);
                short8 bf1 = *(const short8*)(&Ks[nt*16 + l16][32 + quad*8]);
                f32x4 c = (f32x4){0.f,0.f,0.f,0.f};
                c = __builtin_amdgcn_mfma_f32_16x16x32_bf16(qf0, bf0, c, 0, 0, 0);
                c = __builtin_amdgcn_mfma_f32_16x16x32_bf16(qf1, bf1, c, 0, 0, 0);
                #pragma unroll
                for (int r = 0; r < 4; ++r) s[nt][r] = c[r];
            }
            #pragma unroll
            for (int r = 0; r < 4; ++r) {
                unsigned int w0 = mbits[mbase[r] + kt*2];
                unsigned int w1 = mbits[mbase[r] + kt*2 + 1];
                #pragma unroll
                for (int nt = 0; nt < 4; ++nt) {
                    unsigned int w = (nt < 2) ? w0 : w1;
                    if (!((w >> (((nt&1)<<4) + l16)) & 1u)) s[nt][r] = -1e30f;
                }
                float smax = fmaxf(fmaxf(s[0][r], s[1][r]), fmaxf(s[2][r], s[3][r]));
                float mn = fmaxf(mloc[r], smax);
                float corr = __expf(mloc[r] - mn);
                float ps = __expf(s[0][r]-mn) + __expf(s[1][r]-mn)
                         + __expf(s[2][r]-mn) + __expf(s[3][r]-mn);
                lloc[r] = lloc[r]*corr + ps;
                mloc[r] = mn;
            }
        }
    }
    // cross-lane merge over the 16 lanes sharing each q-row
    float mrow[4], rinv[4];
    #pragma unroll
    for (int r = 0; r < 4; ++r) {
        #pragma unroll
        for (int off = 1; off < 16; off <<= 1) {
            float mo = __shfl_xor(mloc[r], off);
            float lo = __shfl_xor(lloc[r], off);
            float mn = fmaxf(mloc[r], mo);
            lloc[r] = lloc[r]*__expf(mloc[r]-mn) + lo*__expf(mo-mn);
            mloc[r] = mn;
        }
        mrow[r] = mloc[r];
        rinv[r] = 1.f / lloc[r];
    }

    // ---- pass 2: recompute, stage P, burst-store attn full lines, PV from LDS ----
    f32x4 oacc[4];
    #pragma unroll
    for (int i = 0; i < 4; ++i) oacc[i] = (f32x4){0.f,0.f,0.f,0.f};
    float* attn_b = attn + (size_t)bh * LL * LL;
    int rr8 = lane >> 3, ccs = (lane & 7) * 4;
    float* sb0 = attn_b + (size_t)(q0 + rr8)*LL;
    float* sb1 = sb0 + (size_t)8*LL;

    {
        const unsigned short* kg = Kb + (size_t)srow*DKK + scol;
        short8 ka = *(const short8*)(kg);
        short8 kb2 = *(const short8*)(kg + 8);
        const unsigned short* vg = Vb + (size_t)srow*LL + scol;
        short8 va = *(const short8*)(vg);
        short8 vb2 = *(const short8*)(vg + 8);
        for (int kt = 0; kt < 32; ++kt) {
            __syncthreads();
            *(short8*)(&Ks[srow][scol])   = ka;
            *(short8*)(&Ks[srow][scol+8]) = kb2;
            *(short8*)(&Vs[srow][scol])   = va;
            *(short8*)(&Vs[srow][scol+8]) = vb2;
            if (kt < 31) {
                const unsigned short* kn = Kb + (size_t)((kt+1)*64 + srow)*DKK + scol;
                ka = *(const short8*)(kn);
                kb2 = *(const short8*)(kn + 8);
                const unsigned short* vn = Vb + (size_t)srow*LL + (kt+1)*64 + scol;
                va = *(const short8*)(vn);
                vb2 = *(const short8*)(vn + 8);
            }
            __syncthreads();
            #pragma unroll
            for (int nt = 0; nt < 4; ++nt) {
                short8 bf0 = *(const short8*)(&Ks[nt*16 + l16][quad*8]);
                short8 bf1 = *(const short8*)(&Ks[nt*16 + l16][32 + quad*8]);
                f32x4 c = (f32x4){0.f,0.f,0.f,0.f};
                c = __builtin_amdgcn_mfma_f32_16x16x32_bf16(qf0, bf0, c, 0, 0, 0);
                c = __builtin_amdgcn_mfma_f32_16x16x32_bf16(qf1, bf1, c, 0, 0, 0);
                #pragma unroll
                for (int r = 0; r < 4; ++r) {
                    unsigned int w = mbits[mbase[r] + kt*2 + (nt>>1)];
                    int bit = (w >> (((nt&1)<<4) + l16)) & 1;
                    float p = bit ? __expf(c[r] - mrow[r]) * rinv[r] : 0.f;
                    Pl[wv][quad*4 + r][nt*16 + l16] = f2bf(p);
                }
            }
            // burst: this wave's 16x64 P tile -> attn as f32 full 128B lines
            #pragma unroll
            for (int ci = 0; ci < 2; ++ci) {
                ushort4 p0 = *(const ushort4*)(&Pl[wv][rr8][ci*32 + ccs]);
                ushort4 p1 = *(const ushort4*)(&Pl[wv][8 + rr8][ci*32 + ccs]);
                f32x4 f0, f1;
                f0[0]=bf2f(p0.x); f0[1]=bf2f(p0.y); f0[2]=bf2f(p0.z); f0[3]=bf2f(p0.w);
                f1[0]=bf2f(p1.x); f1[1]=bf2f(p1.y); f1[2]=bf2f(p1.z); f1[3]=bf2f(p1.w);
                *(f32x4*)(sb0 + kt*64 + ci*32 + ccs) = f0;
                *(f32x4*)(sb1 + kt*64 + ci*32 + ccs) = f1;
            }
            // PV from LDS (intra-wave Pl write->read, no barrier)
            #pragma unroll
            for (int c2 = 0; c2 < 2; ++c2) {
                short8 pf = *(const short8*)(&Pl[wv][l16][c2*32 + quad*8]);
                #pragma unroll
                for (int dt = 0; dt < 4; ++dt) {
                    short8 vf = *(const short8*)(&Vs[dt*16 + l16][c2*32 + quad*8]);
                    oacc[dt] = __builtin_amdgcn_mfma_f32_16x16x32_bf16(pf, vf, oacc[dt], 0, 0, 0);
                }
            }
        }
    }

    #pragma unroll
    for (int dt = 0; dt < 4; ++dt) {
        #pragma unroll
        for (int r = 0; r < 4; ++r) {
            int row = q0 + quad*4 + r;
            size_t m = (size_t)b*LL + row;
            AO[m*DD + h*DKK + dt*16 + l16] = f2bf(oacc[dt][r]);
        }
    }
}

extern "C" void kernel_launch(void* const* d_in, const int* in_sizes, int n_in,
                              void* d_out, int out_size, void* d_ws, size_t ws_size,
                              hipStream_t stream) {
    const float* q  = (const float*)d_in[0];
    const float* k  = (const float*)d_in[1];
    const float* v  = (const float*)d_in[2];
    const int* mask = (const int*)d_in[3];
    const float* gq = (const float*)d_in[4];
    const float* bq = (const float*)d_in[5];
    const float* gk = (const float*)d_in[6];
    const float* bk = (const float*)d_in[7];
    const float* gv = (const float*)d_in[8];
    const float* bv = (const float*)d_in[9];
    const float* Wq = (const float*)d_in[10];
    const float* Wk = (const float*)d_in[11];
    const float* Wv = (const float*)d_in[12];
    const float* Wfc = (const float*)d_in[13];

    // workspace layout (ushort elements)
    unsigned short* Wb = (unsigned short*)d_ws;        // 4 x 1M bf16          (8 MB)
    unsigned short* xn = Wb + (size_t)4*DD*DD;         // 3 x 4.19M bf16       (24 MB)
    unsigned short* qh = xn + (size_t)3*BB*LL*DD;      // 4.19M bf16           (8 MB)
    unsigned short* kh = qh + (size_t)BB*LL*DD;        // 4.19M bf16           (8 MB)
    unsigned short* vT = kh + (size_t)BB*LL*DD;        // 4.19M bf16           (8 MB)
    unsigned int* mb  = (unsigned int*)(vT + (size_t)BB*LL*DD);  // 1.05 MB
    unsigned short* AO = xn;                           // alias: xn dead after projections

    float* out_main = (float*)d_out;                       // (B,L,D)
    float* out_attn = out_main + (size_t)BB*LL*DD;         // (B,H,L,L)

    dim3 blk(256);
    k_prep<<<dim3(49152), blk, 0, stream>>>(Wq, Wk, Wv, Wfc, Wb,
                                            mask, (unsigned long long*)mb,
                                            q, k, v, gq, bq, gk, bk, gv, bv, xn);
    k_gemm3<<<dim3(3072), blk, 0, stream>>>(xn, Wb, qh, kh, vT);
    k_attn<<<dim3(1024), blk, 0, stream>>>(qh, kh, vT, mb, out_attn, AO);
    k_gemmF<<<dim3(1024), blk, 0, stream>>>(AO, Wb + (size_t)3*DD*DD, out_main, q);
}